// Round 9
// baseline (210.506 us; speedup 1.0000x reference)
//
#include <hip/hip_runtime.h>
#include <hip/hip_bf16.h>
#include <math.h>

// Problem constants (B=1): S=4096, D=128, NHEADS=4, hd=32, N_COE=50, N_SCALES=4, THRE=5
//
// ws layout (floats):
//   eig   @ 0        (524288)
//   qkv   @ 524288   (only Q panel used, f32)
//   Oe    @ 2097152  (4*4096*128)
//   E     @ 4194304  (4*4*4096)
//   xsum  @ 4259840  (128)
//   Khi_g @ 4260352  [h][key][d] bf16 hi
//   Klo_g @ 4522496  [h][key][d] bf16 lo
//   Vt_g  @ 4784640  [h*32+d][key] bf16

#define KSPLIT 4

typedef __attribute__((ext_vector_type(8))) short short8;   // 8 bf16
typedef __attribute__((ext_vector_type(4))) float f32x4;

__device__ inline unsigned short f2bf(float x) {            // RNE f32->bf16 bits
    unsigned u = __float_as_uint(x);
    return (unsigned short)((u + 0x7FFFu + ((u >> 16) & 1u)) >> 16);
}
__device__ inline float bf2f(unsigned short h) { return __uint_as_float(((unsigned)h) << 16); }
__device__ inline unsigned pk_bf16(float lo, float hi) {    // packed RNE pair (v_cvt_pk_bf16_f32)
    __hip_bfloat162 h = __float22bfloat162_rn(make_float2(lo, hi));
    return *reinterpret_cast<unsigned*>(&h);
}

// ---------------- K1: fused sine-encoding + eig GEMM + LN1 + qkv GEMM ----------------
// 16 rows/block, 256 blocks, 512 threads. Half-panel (64-row) double-buffered weight
// staging: next half's global loads issued before current half's GEMM, ds_write after.
__global__ __launch_bounds__(512) void k_embed(const float* __restrict__ eve,
    const float* __restrict__ eigW, const float* __restrict__ ebias,
    const float* __restrict__ g, const float* __restrict__ b,
    const float* __restrict__ inW, const float* __restrict__ inb,
    float* __restrict__ eig, float* __restrict__ qkv, unsigned short* __restrict__ Khi_g,
    unsigned short* __restrict__ Klo_g, unsigned short* __restrict__ Vt_g,
    float* __restrict__ xsum)
{
    __shared__ __align__(16) float wsh[2][65 * 128];       // 2 x 33.25 KB half-panels
    __shared__ __align__(16) float se[16][132];            // [0..63]=sin, [64..127]=cos, [128]=e
    __shared__ __align__(16) float xn[16][132];            // LN1 output
    __shared__ __align__(16) unsigned short vsh[16][136];  // [key][d]
    const int t = threadIdx.x;                             // 0..511
    const int r0 = blockIdx.x * 16;
    if (blockIdx.x == 0 && t < 128) xsum[t] = 0.f;         // folded memset

    const float4* __restrict__ eigW4 = (const float4*)eigW;
    const float4* __restrict__ inW4  = (const float4*)inW;
    float4 pf0 = eigW4[t];
    float4 pf1 = eigW4[t + 512];
    float4 pf2 = eigW4[t + 1024];
    float4 pf3 = eigW4[t + 1536];
    float4 pf4;
    if (t < 32) pf4 = eigW4[t + 2048];

    {   // Phase A: sin/cos (16 rows x 32 threads/row x 2 j)
        const int rr = t >> 5, l5 = t & 31;
        const float e = eve[r0 + rr];
        if (l5 == 0) se[rr][128] = e;
        #pragma unroll
        for (int jj = 0; jj < 2; ++jj) {
            const int j = l5 * 2 + jj;
            const float div = __expf(-0.07195578415606394f * (float)(2 * j));
            const float pe = e * 100.0f * div;    // |pe| <= 200 rad
            se[rr][j]      = __sinf(pe);
            se[rr][64 + j] = __cosf(pe);
        }
    }
    {   // write eigW h0 -> buf0
        float4* dst = (float4*)wsh[0];
        dst[t] = pf0; dst[t + 512] = pf1; dst[t + 1024] = pf2; dst[t + 1536] = pf3;
        if (t < 32) dst[t + 2048] = pf4;
    }
    const int r  = t >> 5;            // row 0..15 (== kb for staging)
    const int c0 = (t & 31) * 4;
    const int kb = t >> 5, c4 = t & 31;
    float a0, a1, a2, a3;
    float xa[4];

    // ---- phase E0: eig GEMM k=0..63 from buf0; prefetch eigW h1 -> buf1
    __syncthreads();
    pf0 = eigW4[2080 + t];        pf1 = eigW4[2080 + t + 512];
    pf2 = eigW4[2080 + t + 1024]; pf3 = eigW4[2080 + t + 1536];
    {
        const float* __restrict__ W = wsh[0];
        const float4 w0 = *(const float4*)&W[c0];
        const float ea = se[r][128];
        a0 = ea * w0.x; a1 = ea * w0.y; a2 = ea * w0.z; a3 = ea * w0.w;
        #pragma unroll 8
        for (int k = 0; k < 64; ++k) {            // se[.][k] pairs eigW row k+1
            const float xv = se[r][k];
            const float4 wk = *(const float4*)&W[(k + 1) * 128 + c0];
            a0 = fmaf(xv, wk.x, a0); a1 = fmaf(xv, wk.y, a1);
            a2 = fmaf(xv, wk.z, a2); a3 = fmaf(xv, wk.w, a3);
        }
    }
    {   float4* dst = (float4*)wsh[1];
        dst[t] = pf0; dst[t + 512] = pf1; dst[t + 1024] = pf2; dst[t + 1536] = pf3;
    }
    // ---- phase E1: eig GEMM k=64..127 from buf1; prefetch inW(p0,h0) -> buf0; LN1
    __syncthreads();
    pf0 = inW4[(size_t)(kb +  0) * 96 + c4];
    pf1 = inW4[(size_t)(kb + 16) * 96 + c4];
    pf2 = inW4[(size_t)(kb + 32) * 96 + c4];
    pf3 = inW4[(size_t)(kb + 48) * 96 + c4];
    {
        const float* __restrict__ W = wsh[1];
        #pragma unroll 8
        for (int k = 64; k < 128; ++k) {          // local row k-64 holds eigW row k+1
            const float xv = se[r][k];
            const float4 wk = *(const float4*)&W[(k - 64) * 128 + c0];
            a0 = fmaf(xv, wk.x, a0); a1 = fmaf(xv, wk.y, a1);
            a2 = fmaf(xv, wk.z, a2); a3 = fmaf(xv, wk.w, a3);
        }
        const float4 bb = *(const float4*)&ebias[c0];
        xa[0] = a0 + bb.x; xa[1] = a1 + bb.y; xa[2] = a2 + bb.z; xa[3] = a3 + bb.w;
        *(float4*)&eig[(size_t)(r0 + r) * 128 + c0] = make_float4(xa[0], xa[1], xa[2], xa[3]);
        // LN1 (half-wave local)
        float sa = (xa[0] + xa[1]) + (xa[2] + xa[3]);
        float qa = (xa[0] * xa[0] + xa[1] * xa[1]) + (xa[2] * xa[2] + xa[3] * xa[3]);
        #pragma unroll
        for (int m = 1; m < 32; m <<= 1) {
            sa += __shfl_xor(sa, m, 32); qa += __shfl_xor(qa, m, 32);
        }
        const float ma = sa * (1.f / 128.f);
        const float ia = 1.f / sqrtf(qa * (1.f / 128.f) - ma * ma + 1e-5f);
        const float4 gg = *(const float4*)&g[c0];
        const float4 lb = *(const float4*)&b[c0];
        *(float4*)&xn[r][c0] = make_float4((xa[0] - ma) * ia * gg.x + lb.x,
                                           (xa[1] - ma) * ia * gg.y + lb.y,
                                           (xa[2] - ma) * ia * gg.z + lb.z,
                                           (xa[3] - ma) * ia * gg.w + lb.w);
    }
    {   float4* dst = (float4*)wsh[0];
        dst[t] = pf0; dst[t + 512] = pf1; dst[t + 1024] = pf2; dst[t + 1536] = pf3;
    }
    // ---- qkv panels: 6 half-phases, buf parity = hh
    const int row = r0 + r;
    float A0, A1, A2, A3;
    #pragma unroll
    for (int p = 0; p < 3; ++p) {
        #pragma unroll
        for (int hh = 0; hh < 2; ++hh) {
            __syncthreads();
            const bool last = (p == 2 && hh == 1);
            if (!last) {
                const int np = p + hh, nh = hh ^ 1;
                pf0 = inW4[(size_t)(kb +  0 + nh * 64) * 96 + np * 32 + c4];
                pf1 = inW4[(size_t)(kb + 16 + nh * 64) * 96 + np * 32 + c4];
                pf2 = inW4[(size_t)(kb + 32 + nh * 64) * 96 + np * 32 + c4];
                pf3 = inW4[(size_t)(kb + 48 + nh * 64) * 96 + np * 32 + c4];
            }
            if (hh == 0) {
                const float4 bb = *(const float4*)&inb[p * 128 + c0];
                A0 = bb.x; A1 = bb.y; A2 = bb.z; A3 = bb.w;
            }
            const float* __restrict__ W = wsh[hh];
            #pragma unroll 8
            for (int k2 = 0; k2 < 64; ++k2) {
                const float xv = xn[r][hh * 64 + k2];
                const float4 wk = *(const float4*)&W[k2 * 128 + c0];
                A0 = fmaf(xv, wk.x, A0); A1 = fmaf(xv, wk.y, A1);
                A2 = fmaf(xv, wk.z, A2); A3 = fmaf(xv, wk.w, A3);
            }
            if (!last) {
                float4* dst = (float4*)wsh[hh ^ 1];
                dst[t] = pf0; dst[t + 512] = pf1; dst[t + 1024] = pf2; dst[t + 1536] = pf3;
            }
            if (hh == 1) {
                if (p == 0) {          // Q: f32
                    *(float4*)&qkv[(size_t)row * 384 + c0] = make_float4(A0, A1, A2, A3);
                } else if (p == 1) {   // K: bf16 hi/lo, [h][key][d]
                    const int h = c0 >> 5, d = c0 & 31;
                    float A[4] = {A0, A1, A2, A3};
                    unsigned short h4[4], l4v[4];
                    #pragma unroll
                    for (int i = 0; i < 4; ++i) { h4[i] = f2bf(A[i]); l4v[i] = f2bf(A[i] - bf2f(h4[i])); }
                    *(uint2*)&Khi_g[((size_t)h * 4096 + row) * 32 + d] = *(uint2*)h4;
                    *(uint2*)&Klo_g[((size_t)h * 4096 + row) * 32 + d] = *(uint2*)l4v;
                } else {               // V: bf16, row-major [key][d] in LDS
                    unsigned short v4[4];
                    float A[4] = {A0, A1, A2, A3};
                    #pragma unroll
                    for (int i = 0; i < 4; ++i) v4[i] = f2bf(A[i]);
                    *(uint2*)&vsh[r][c0] = *(uint2*)v4;
                }
            }
        }
    }
    __syncthreads();
    if (t < 128) {   // V transpose flush: column d = t across 16 keys
        __align__(16) unsigned short tmp[16];
        #pragma unroll
        for (int k2 = 0; k2 < 16; ++k2) tmp[k2] = vsh[k2][t];
        *(uint4*)&Vt_g[(size_t)t * 4096 + r0]     = *(uint4*)&tmp[0];
        *(uint4*)&Vt_g[(size_t)t * 4096 + r0 + 8] = *(uint4*)&tmp[8];
    }
}

// ---------------- K3: MFMA flash attention — register-resident K/V, barrier-free ----------------
// K/V fragments are read directly from global (L2-resident; wave-level access is fully
// coalesced: K = contiguous 1KB per load, V = 16 fully-used 64B lines). K is register
// double-buffered one chunk ahead; V issued early per chunk. LDS holds ONLY the
// per-wave P transpose (no cross-wave data => zero __syncthreads; same-wave
// ds_write->ds_read ordering is compiler-inserted lgkmcnt).
#define PSTR 72

#define QK_TILES_REG(MASKED)                                                      \
    _Pragma("unroll")                                                             \
    for (int tile = 0; tile < 4; ++tile) {                                        \
        f32x4 S = {0.f, 0.f, 0.f, 0.f};                                           \
        __builtin_amdgcn_s_setprio(1);                                            \
        S = __builtin_amdgcn_mfma_f32_16x16x32_bf16(khc[tile], qhi, S, 0, 0, 0);  \
        S = __builtin_amdgcn_mfma_f32_16x16x32_bf16(kwc[tile], qhi, S, 0, 0, 0);  \
        S = __builtin_amdgcn_mfma_f32_16x16x32_bf16(khc[tile], qlo, S, 0, 0, 0);  \
        __builtin_amdgcn_s_setprio(0);                                            \
        const int kg0 = keybase + tile * 16 + quad * 4;                           \
        const float p0 = (!(MASKED) || (kg0 + 0 < nk)) ? __expf(S[0]) : 0.f;      \
        const float p1 = (!(MASKED) || (kg0 + 1 < nk)) ? __expf(S[1]) : 0.f;      \
        const float p2 = (!(MASKED) || (kg0 + 2 < nk)) ? __expf(S[2]) : 0.f;      \
        const float p3 = (!(MASKED) || (kg0 + 3 < nk)) ? __expf(S[3]) : 0.f;      \
        elane += (p0 + p1) + (p2 + p3);                                           \
        *(uint2*)&Pw[l * PSTR + tile * 16 + quad * 4] =                           \
            make_uint2(pk_bf16(p0, p1), pk_bf16(p2, p3));                         \
    }

__global__ __launch_bounds__(256) void k_attn(const float* __restrict__ qkv,
    const unsigned short* __restrict__ Khi_g, const unsigned short* __restrict__ Klo_g,
    const unsigned short* __restrict__ Vt_g,
    const int* __restrict__ sele, float* __restrict__ Oe, float* __restrict__ E)
{
    __shared__ __align__(16) unsigned short Pb[4][16 * PSTR];   // per-wave only

    const int t = threadIdx.x;
    const int lane = t & 63;
    const int l = lane & 15;
    const int quad = lane >> 4;
    const int wv = __builtin_amdgcn_readfirstlane(t >> 6);
    const int qb = blockIdx.x;
    const int h  = blockIdx.y;
    const int ks = blockIdx.z;
    const int nk = sele[0];

    short8 qhi, qlo;
    {
        const float* __restrict__ qr = qkv + (size_t)(qb * 64 + wv * 16 + l) * 384 + h * 32 + quad * 8;
        const float4 a = *(const float4*)qr;
        const float4 b = *(const float4*)(qr + 4);
        const float sc = 0.17677669529663687f;   // 1/sqrt(32)
        float v[8] = {a.x * sc, a.y * sc, a.z * sc, a.w * sc, b.x * sc, b.y * sc, b.z * sc, b.w * sc};
        #pragma unroll
        for (int j = 0; j < 8; ++j) {
            const unsigned short hb = f2bf(v[j]);
            qhi[j] = (short)hb;
            qlo[j] = (short)f2bf(v[j] - bf2f(hb));
        }
    }
    f32x4 accO0 = {0.f, 0.f, 0.f, 0.f};
    f32x4 accO1 = {0.f, 0.f, 0.f, 0.f};
    float elane = 0.f;

    // per-lane global fragment bases
    // K: key = ks*1024 + ch*64 + tile*16 + l, d = quad*8 (wave covers contiguous 1KB)
    const size_t kofs0 = ((size_t)h * 4096 + ks * 1024 + l) * 32 + quad * 8;
    const unsigned short* __restrict__ pKhi = Khi_g + kofs0;
    const unsigned short* __restrict__ pKlo = Klo_g + kofs0;
    // V: row h*32 + l (and +16), key = ks*1024 + ch*64 + step*32 + quad*8
    const size_t vofs0 = ((size_t)h * 32 + l) * 4096 + ks * 1024 + quad * 8;
    const unsigned short* __restrict__ pV0 = Vt_g + vofs0;
    const unsigned short* __restrict__ pV1 = Vt_g + vofs0 + (size_t)16 * 4096;

    unsigned short* __restrict__ Pw = Pb[wv];

    short8 khc[4], kwc[4], khn[4], kwn[4];
    #pragma unroll
    for (int tile = 0; tile < 4; ++tile) {       // chunk 0 K -> regs
        khc[tile] = *(const short8*)(pKhi + (size_t)(tile * 16) * 32);
        kwc[tile] = *(const short8*)(pKlo + (size_t)(tile * 16) * 32);
    }

    for (int ch = 0; ch < 16; ++ch) {
        const int keybase = ks * 1024 + ch * 64;
        if (ch < 15) {                           // prefetch next chunk K into regs
            #pragma unroll
            for (int tile = 0; tile < 4; ++tile) {
                khn[tile] = *(const short8*)(pKhi + (size_t)((ch + 1) * 64 + tile * 16) * 32);
                kwn[tile] = *(const short8*)(pKlo + (size_t)((ch + 1) * 64 + tile * 16) * 32);
            }
        }
        // V for this chunk: issue early, consumed after QK+exp (~300 cyc of cover)
        short8 vb0[2], vb1[2];
        #pragma unroll
        for (int step = 0; step < 2; ++step) {
            vb0[step] = *(const short8*)(pV0 + ch * 64 + step * 32);
            vb1[step] = *(const short8*)(pV1 + ch * 64 + step * 32);
        }
        if (keybase + 64 <= nk) {                // wave-uniform: no per-key masking
            QK_TILES_REG(0)
        } else {
            QK_TILES_REG(1)
        }
        #pragma unroll
        for (int step = 0; step < 2; ++step) {
            const short8 pa = *(const short8*)&Pw[l * PSTR + step * 32 + quad * 8];
            __builtin_amdgcn_s_setprio(1);
            accO0 = __builtin_amdgcn_mfma_f32_16x16x32_bf16(pa, vb0[step], accO0, 0, 0, 0);
            accO1 = __builtin_amdgcn_mfma_f32_16x16x32_bf16(pa, vb1[step], accO1, 0, 0, 0);
            __builtin_amdgcn_s_setprio(0);
        }
        #pragma unroll
        for (int tile = 0; tile < 4; ++tile) {   // swap K double-buffer
            khc[tile] = khn[tile];
            kwc[tile] = kwn[tile];
        }
    }
    elane += __shfl_xor(elane, 16, 64);
    elane += __shfl_xor(elane, 32, 64);
    const int qrow0 = qb * 64 + wv * 16;
    if (lane < 16)
        E[((size_t)ks * 4 + h) * 4096 + qrow0 + l] = elane;
    #pragma unroll
    for (int r = 0; r < 4; ++r) {
        const size_t row = qrow0 + quad * 4 + r;
        Oe[((size_t)ks * 4096 + row) * 128 + h * 32 + l]      = accO0[r];
        Oe[((size_t)ks * 4096 + row) * 128 + h * 32 + 16 + l] = accO1[r];
    }
}

// ---------------- K4: fold + out-proj + residual + LN2 + FFN + column-sum ----------------
// 16 rows/block, 256 blocks, 512 threads. Half-panel double-buffered weight staging;
// 6 GEMM half-phases (outW, W1, W2 x 2 halves), one barrier each.
__global__ __launch_bounds__(512) void k_ffn(const float* __restrict__ eig,
    const float* __restrict__ Oe, const float* __restrict__ E,
    const float* __restrict__ outW, const float* __restrict__ outb,
    const float* __restrict__ lg, const float* __restrict__ lb,
    const float* __restrict__ W1, const float* __restrict__ b1,
    const float* __restrict__ W2, const float* __restrict__ b2,
    const int* __restrict__ sele, float* __restrict__ xsum)
{
    __shared__ __align__(16) float wsh[2][64 * 128];  // 2 x 32 KB half-panels
    __shared__ __align__(16) float sA[16][132];       // O rows, later gelu(h)
    __shared__ __align__(16) float xn[16][132];       // LN2 output
    __shared__ __align__(16) float cs[16][132];       // per-row masked contributions
    const int t = threadIdx.x;                        // 0..511
    const int r0 = blockIdx.x * 16;
    const int r  = t >> 5;
    const int c0 = (t & 31) * 4;

    const float4* __restrict__ Wp0 = (const float4*)outW;
    const float4* __restrict__ Wp1 = (const float4*)W1;
    const float4* __restrict__ Wp2 = (const float4*)W2;

    // prefetch outW h0 before fold
    float4 pf0 = Wp0[t], pf1 = Wp0[t + 512], pf2 = Wp0[t + 1024], pf3 = Wp0[t + 1536];

    {   // fold 4 key-slots + divide by E
        const int h = c0 >> 5;
        float es = 0.f;
        float v[4] = {0.f, 0.f, 0.f, 0.f};
        #pragma unroll
        for (int ks = 0; ks < KSPLIT; ++ks) {
            es += E[((size_t)ks * 4 + h) * 4096 + r0 + r];
            const float4 o1 = *(const float4*)&Oe[((size_t)ks * 4096 + r0 + r) * 128 + c0];
            v[0] += o1.x; v[1] += o1.y; v[2] += o1.z; v[3] += o1.w;
        }
        const float rcp = 1.f / es;
        *(float4*)&sA[r][c0] = make_float4(v[0] * rcp, v[1] * rcp, v[2] * rcp, v[3] * rcp);
    }
    {   float4* dst = (float4*)wsh[0];
        dst[t] = pf0; dst[t + 512] = pf1; dst[t + 1024] = pf2; dst[t + 1536] = pf3;
    }

    float x2[4];
    float A0, A1, A2, A3;
    #pragma unroll
    for (int gphase = 0; gphase < 6; ++gphase) {
        const int gg = gphase >> 1, hh = gphase & 1;
        __syncthreads();
        if (gphase < 5) {
            const int nid = gphase + 1;
            const int ng = nid >> 1, nh = nid & 1;
            const float4* __restrict__ src = (ng == 0) ? Wp0 : (ng == 1 ? Wp1 : Wp2);
            pf0 = src[nh * 2048 + t];        pf1 = src[nh * 2048 + t + 512];
            pf2 = src[nh * 2048 + t + 1024]; pf3 = src[nh * 2048 + t + 1536];
        }
        if (hh == 0) {
            const float* bias = (gg == 0) ? outb : (gg == 1 ? b1 : b2);
            const float4 bb = *(const float4*)&bias[c0];
            A0 = bb.x; A1 = bb.y; A2 = bb.z; A3 = bb.w;
        }
        const float* __restrict__ W = wsh[hh];
        const float* __restrict__ act = (gg == 1) ? &xn[r][0] : &sA[r][0];
        #pragma unroll 8
        for (int k2 = 0; k2 < 64; ++k2) {
            const float xv = act[hh * 64 + k2];
            const float4 wk = *(const float4*)&W[k2 * 128 + c0];
            A0 = fmaf(xv, wk.x, A0); A1 = fmaf(xv, wk.y, A1);
            A2 = fmaf(xv, wk.z, A2); A3 = fmaf(xv, wk.w, A3);
        }
        if (gphase < 5) {
            float4* dst = (float4*)wsh[hh ^ 1];
            dst[t] = pf0; dst[t + 512] = pf1; dst[t + 1024] = pf2; dst[t + 1536] = pf3;
        }
        if (hh == 1) {
            if (gg == 0) {      // residual + LN2 -> xn (half-wave local)
                const float4 ea = *(const float4*)&eig[(size_t)(r0 + r) * 128 + c0];
                x2[0] = ea.x + A0; x2[1] = ea.y + A1; x2[2] = ea.z + A2; x2[3] = ea.w + A3;
                float sa = (x2[0] + x2[1]) + (x2[2] + x2[3]);
                float qa = (x2[0] * x2[0] + x2[1] * x2[1]) + (x2[2] * x2[2] + x2[3] * x2[3]);
                #pragma unroll
                for (int m = 1; m < 32; m <<= 1) {
                    sa += __shfl_xor(sa, m, 32); qa += __shfl_xor(qa, m, 32);
                }
                const float ma = sa * (1.f / 128.f);
                const float ia = 1.f / sqrtf(qa * (1.f / 128.f) - ma * ma + 1e-5f);
                const float4 gg4 = *(const float4*)&lg[c0];
                const float4 bb4 = *(const float4*)&lb[c0];
                *(float4*)&xn[r][c0] = make_float4((x2[0] - ma) * ia * gg4.x + bb4.x,
                                                   (x2[1] - ma) * ia * gg4.y + bb4.y,
                                                   (x2[2] - ma) * ia * gg4.z + bb4.z,
                                                   (x2[3] - ma) * ia * gg4.w + bb4.w);
            } else if (gg == 1) {   // exact gelu -> sA (half-wave local)
                *(float4*)&sA[r][c0] = make_float4(
                    0.5f * A0 * (1.f + erff(A0 * 0.70710678118654752f)),
                    0.5f * A1 * (1.f + erff(A1 * 0.70710678118654752f)),
                    0.5f * A2 * (1.f + erff(A2 * 0.70710678118654752f)),
                    0.5f * A3 * (1.f + erff(A3 * 0.70710678118654752f)));
            } else {                // FFN2 + residual + masked contributions
                const int nsel = sele[0];
                const bool ina = (r0 + r) < nsel;
                *(float4*)&cs[r][c0] = ina ? make_float4(x2[0] + A0, x2[1] + A1, x2[2] + A2, x2[3] + A3)
                                           : make_float4(0.f, 0.f, 0.f, 0.f);
            }
        }
    }
    __syncthreads();
    if (t < 128) {
        float s = 0.f;
        #pragma unroll
        for (int rr = 0; rr < 16; ++rr) s += cs[rr][t];
        atomicAdd(&xsum[t], s);
    }
}

// ---------------- K5+K6 merged: coefficients (redundant per block) + Chebyshev ----------------
// 256 blocks x 128 threads, 16 eigenvalues/block; thread = one (elem, chain) pair.
__global__ __launch_bounds__(128) void k_tail(const float* __restrict__ eve,
    const float* __restrict__ xsum,
    const float* __restrict__ dscW, const float* __restrict__ dscb,
    const float* __restrict__ dwvW, const float* __restrict__ dwvb,
    const float* __restrict__ dssW, const float* __restrict__ dssb,
    const int* __restrict__ len, const int* __restrict__ sele,
    float* __restrict__ out)
{
    __shared__ float xs[128];
    __shared__ float val[104];
    __shared__ float s2[2];
    __shared__ float csc[50], cwv[50], cssh[4];
    __shared__ float sv[16][6];
    const int t = threadIdx.x;
    xs[t] = xsum[t];
    __syncthreads();
    if (t < 104) {
        const float invl = 1.f / ((float)len[0] + 1e-8f);
        const float ns = (float)sele[0];
        const float* Wp; int stride, col; float bias;
        if (t < 50)       { Wp = dscW; stride = 50; col = t;       bias = dscb[t]; }
        else if (t < 100) { Wp = dwvW; stride = 50; col = t - 50;  bias = dwvb[t - 50]; }
        else              { Wp = dssW; stride = 4;  col = t - 100; bias = dssb[t - 100]; }
        float a = 0.f;
        #pragma unroll 4
        for (int k = 0; k < 128; ++k) a = fmaf(xs[k], Wp[k * stride + col], a);
        a = (a + ns * bias) * invl;
        val[t] = 1.f / (1.f + __expf(-a));
    }
    __syncthreads();
    if (t == 0) { float s = 0.f; for (int i = 0; i < 50; ++i) s += val[i]; s2[0] = s; }
    if (t == 1) { float s = 0.f; for (int i = 0; i < 50; ++i) s += val[50 + i]; s2[1] = s; }
    __syncthreads();
    if (t < 50) {
        csc[t] = val[t] / (s2[0] + 1e-8f);
        cwv[t] = val[50 + t] / (s2[1] + 1e-8f);
    } else if (t >= 100 && t < 104) {
        cssh[t - 100] = val[t] * 5.0f;   // THRE
    }
    __syncthreads();
    const int e_i = t / 5, c = t - e_i * 5;       // elem 0..15, chain 0..4
    if (t < 80) {
        const float e = eve[blockIdx.x * 16 + e_i];
        float y;
        if (c == 0) y = e - 1.f;
        else { float f = e * cssh[c - 1]; if (f > 2.f) f = 0.f; y = f - 1.f; }
        const float* __restrict__ cf = (c == 0) ? csc : cwv;
        float te = 1.f, to = y;
        float u = (c == 0) ? to : te;
        float a = cf[0] * (0.5f * (1.f - u));
        const float y2 = 2.f * y;
        for (int i = 1; i < 50; ++i) {
            te = fmaf(y2, to, -te);
            to = fmaf(y2, te, -to);
            u = (c == 0) ? to : te;
            a = fmaf(cf[i], 0.5f * (1.f - u), a);
        }
        sv[e_i][c] = a;
    }
    __syncthreads();
    if (t < 80) {
        float n2 = 0.f;
        #pragma unroll
        for (int k = 0; k < 5; ++k) n2 += sv[e_i][k] * sv[e_i][k];
        const float invn = 1.f / (sqrtf(n2) + 1e-8f);
        out[(size_t)(blockIdx.x * 16 + e_i) * 5 + c] = sv[e_i][c] * invn;
    }
}

extern "C" void kernel_launch(void* const* d_in, const int* in_sizes, int n_in,
                              void* d_out, int out_size, void* d_ws, size_t ws_size,
                              hipStream_t stream) {
    const float* eve  = (const float*)d_in[0];
    const int*   len  = (const int*)d_in[1];
    const int*   sele = (const int*)d_in[2];
    const float* eigW = (const float*)d_in[3];
    const float* eigB = (const float*)d_in[4];
    const float* mlg  = (const float*)d_in[5];
    const float* mlb  = (const float*)d_in[6];
    const float* inW  = (const float*)d_in[7];
    const float* inb  = (const float*)d_in[8];
    const float* outW = (const float*)d_in[9];
    const float* outb = (const float*)d_in[10];
    const float* flg  = (const float*)d_in[11];
    const float* flb  = (const float*)d_in[12];
    const float* W1   = (const float*)d_in[13];
    const float* b1   = (const float*)d_in[14];
    const float* W2   = (const float*)d_in[15];
    const float* b2   = (const float*)d_in[16];
    const float* dscW = (const float*)d_in[17];
    const float* dscb = (const float*)d_in[18];
    const float* dwvW = (const float*)d_in[19];
    const float* dwvb = (const float*)d_in[20];
    const float* dssW = (const float*)d_in[21];
    const float* dssb = (const float*)d_in[22];

    float* ws   = (float*)d_ws;
    float* eig  = ws;
    float* qkv  = ws + 524288;
    float* Oe   = ws + 2097152;
    float* E    = ws + 4194304;
    float* xsum = ws + 4259840;
    unsigned short* Khi_g = (unsigned short*)(ws + 4260352);
    unsigned short* Klo_g = (unsigned short*)(ws + 4522496);
    unsigned short* Vt_g  = (unsigned short*)(ws + 4784640);
    float* out  = (float*)d_out;

    k_embed<<<256, 512, 0, stream>>>(eve, eigW, eigB, mlg, mlb, inW, inb,
                                     eig, qkv, Khi_g, Klo_g, Vt_g, xsum);
    k_attn <<<dim3(64, 4, KSPLIT), 256, 0, stream>>>(qkv, Khi_g, Klo_g, Vt_g, sele, Oe, E);
    k_ffn  <<<256, 512, 0, stream>>>(eig, Oe, E, outW, outb, flg, flb, W1, b1, W2, b2, sele, xsum);
    k_tail <<<256, 128, 0, stream>>>(eve, xsum, dscW, dscb, dwvW, dwvb, dssW, dssb, len, sele, out);
}

// Round 10
// 176.512 us; speedup vs baseline: 1.1926x; 1.1926x over previous
//
#include <hip/hip_runtime.h>
#include <hip/hip_bf16.h>
#include <math.h>

// Problem constants (B=1): S=4096, D=128, NHEADS=4, hd=32, N_COE=50, N_SCALES=4, THRE=5
//
// ws layout (floats):
//   eig   @ 0        (524288)
//   qkv   @ 524288   (only Q panel used, f32)
//   Oe    @ 2097152  (4*4096*128)
//   E     @ 4194304  (4*4*4096)
//   xsum  @ 4259840  (128)
//   Khi_g @ 4260352  [h][key][d] bf16 hi
//   Klo_g @ 4522496  [h][key][d] bf16 lo
//   Vt_g  @ 4784640  [h*32+d][key] bf16

#define KSPLIT 4

typedef __attribute__((ext_vector_type(8))) short short8;   // 8 bf16
typedef __attribute__((ext_vector_type(4))) float f32x4;

__device__ inline unsigned short f2bf(float x) {            // RNE f32->bf16 bits
    unsigned u = __float_as_uint(x);
    return (unsigned short)((u + 0x7FFFu + ((u >> 16) & 1u)) >> 16);
}
__device__ inline float bf2f(unsigned short h) { return __uint_as_float(((unsigned)h) << 16); }
__device__ inline unsigned pk_bf16(float lo, float hi) {    // packed RNE pair (v_cvt_pk_bf16_f32)
    __hip_bfloat162 h = __float22bfloat162_rn(make_float2(lo, hi));
    return *reinterpret_cast<unsigned*>(&h);
}

// ---------------- K1: fused sine-encoding + eig GEMM + LN1 + qkv GEMM ----------------
// 16 rows/block, 256 blocks, 512 threads. Half-panel (64-row) double-buffered weight
// staging: next half's global loads issued before current half's GEMM, ds_write after.
__global__ __launch_bounds__(512) void k_embed(const float* __restrict__ eve,
    const float* __restrict__ eigW, const float* __restrict__ ebias,
    const float* __restrict__ g, const float* __restrict__ b,
    const float* __restrict__ inW, const float* __restrict__ inb,
    float* __restrict__ eig, float* __restrict__ qkv, unsigned short* __restrict__ Khi_g,
    unsigned short* __restrict__ Klo_g, unsigned short* __restrict__ Vt_g,
    float* __restrict__ xsum)
{
    __shared__ __align__(16) float wsh[2][65 * 128];       // 2 x 33.25 KB half-panels
    __shared__ __align__(16) float se[16][132];            // [0..63]=sin, [64..127]=cos, [128]=e
    __shared__ __align__(16) float xn[16][132];            // LN1 output
    __shared__ __align__(16) unsigned short vsh[16][136];  // [key][d]
    const int t = threadIdx.x;                             // 0..511
    const int r0 = blockIdx.x * 16;
    if (blockIdx.x == 0 && t < 128) xsum[t] = 0.f;         // folded memset

    const float4* __restrict__ eigW4 = (const float4*)eigW;
    const float4* __restrict__ inW4  = (const float4*)inW;
    float4 pf0 = eigW4[t];
    float4 pf1 = eigW4[t + 512];
    float4 pf2 = eigW4[t + 1024];
    float4 pf3 = eigW4[t + 1536];
    float4 pf4;
    if (t < 32) pf4 = eigW4[t + 2048];

    {   // Phase A: sin/cos (16 rows x 32 threads/row x 2 j)
        const int rr = t >> 5, l5 = t & 31;
        const float e = eve[r0 + rr];
        if (l5 == 0) se[rr][128] = e;
        #pragma unroll
        for (int jj = 0; jj < 2; ++jj) {
            const int j = l5 * 2 + jj;
            const float div = __expf(-0.07195578415606394f * (float)(2 * j));
            const float pe = e * 100.0f * div;    // |pe| <= 200 rad
            se[rr][j]      = __sinf(pe);
            se[rr][64 + j] = __cosf(pe);
        }
    }
    {   // write eigW h0 -> buf0
        float4* dst = (float4*)wsh[0];
        dst[t] = pf0; dst[t + 512] = pf1; dst[t + 1024] = pf2; dst[t + 1536] = pf3;
        if (t < 32) dst[t + 2048] = pf4;
    }
    const int r  = t >> 5;            // row 0..15 (== kb for staging)
    const int c0 = (t & 31) * 4;
    const int kb = t >> 5, c4 = t & 31;
    float a0, a1, a2, a3;
    float xa[4];

    // ---- phase E0: eig GEMM k=0..63 from buf0; prefetch eigW h1 -> buf1
    __syncthreads();
    pf0 = eigW4[2080 + t];        pf1 = eigW4[2080 + t + 512];
    pf2 = eigW4[2080 + t + 1024]; pf3 = eigW4[2080 + t + 1536];
    {
        const float* __restrict__ W = wsh[0];
        const float4 w0 = *(const float4*)&W[c0];
        const float ea = se[r][128];
        a0 = ea * w0.x; a1 = ea * w0.y; a2 = ea * w0.z; a3 = ea * w0.w;
        #pragma unroll 8
        for (int k = 0; k < 64; ++k) {            // se[.][k] pairs eigW row k+1
            const float xv = se[r][k];
            const float4 wk = *(const float4*)&W[(k + 1) * 128 + c0];
            a0 = fmaf(xv, wk.x, a0); a1 = fmaf(xv, wk.y, a1);
            a2 = fmaf(xv, wk.z, a2); a3 = fmaf(xv, wk.w, a3);
        }
    }
    {   float4* dst = (float4*)wsh[1];
        dst[t] = pf0; dst[t + 512] = pf1; dst[t + 1024] = pf2; dst[t + 1536] = pf3;
    }
    // ---- phase E1: eig GEMM k=64..127 from buf1; prefetch inW(p0,h0) -> buf0; LN1
    __syncthreads();
    pf0 = inW4[(size_t)(kb +  0) * 96 + c4];
    pf1 = inW4[(size_t)(kb + 16) * 96 + c4];
    pf2 = inW4[(size_t)(kb + 32) * 96 + c4];
    pf3 = inW4[(size_t)(kb + 48) * 96 + c4];
    {
        const float* __restrict__ W = wsh[1];
        #pragma unroll 8
        for (int k = 64; k < 128; ++k) {          // local row k-64 holds eigW row k+1
            const float xv = se[r][k];
            const float4 wk = *(const float4*)&W[(k - 64) * 128 + c0];
            a0 = fmaf(xv, wk.x, a0); a1 = fmaf(xv, wk.y, a1);
            a2 = fmaf(xv, wk.z, a2); a3 = fmaf(xv, wk.w, a3);
        }
        const float4 bb = *(const float4*)&ebias[c0];
        xa[0] = a0 + bb.x; xa[1] = a1 + bb.y; xa[2] = a2 + bb.z; xa[3] = a3 + bb.w;
        *(float4*)&eig[(size_t)(r0 + r) * 128 + c0] = make_float4(xa[0], xa[1], xa[2], xa[3]);
        // LN1 (half-wave local)
        float sa = (xa[0] + xa[1]) + (xa[2] + xa[3]);
        float qa = (xa[0] * xa[0] + xa[1] * xa[1]) + (xa[2] * xa[2] + xa[3] * xa[3]);
        #pragma unroll
        for (int m = 1; m < 32; m <<= 1) {
            sa += __shfl_xor(sa, m, 32); qa += __shfl_xor(qa, m, 32);
        }
        const float ma = sa * (1.f / 128.f);
        const float ia = 1.f / sqrtf(qa * (1.f / 128.f) - ma * ma + 1e-5f);
        const float4 gg = *(const float4*)&g[c0];
        const float4 lb = *(const float4*)&b[c0];
        *(float4*)&xn[r][c0] = make_float4((xa[0] - ma) * ia * gg.x + lb.x,
                                           (xa[1] - ma) * ia * gg.y + lb.y,
                                           (xa[2] - ma) * ia * gg.z + lb.z,
                                           (xa[3] - ma) * ia * gg.w + lb.w);
    }
    {   float4* dst = (float4*)wsh[0];
        dst[t] = pf0; dst[t + 512] = pf1; dst[t + 1024] = pf2; dst[t + 1536] = pf3;
    }
    // ---- qkv panels: 6 half-phases, buf parity = hh
    const int row = r0 + r;
    float A0, A1, A2, A3;
    #pragma unroll
    for (int p = 0; p < 3; ++p) {
        #pragma unroll
        for (int hh = 0; hh < 2; ++hh) {
            __syncthreads();
            const bool last = (p == 2 && hh == 1);
            if (!last) {
                const int np = p + hh, nh = hh ^ 1;
                pf0 = inW4[(size_t)(kb +  0 + nh * 64) * 96 + np * 32 + c4];
                pf1 = inW4[(size_t)(kb + 16 + nh * 64) * 96 + np * 32 + c4];
                pf2 = inW4[(size_t)(kb + 32 + nh * 64) * 96 + np * 32 + c4];
                pf3 = inW4[(size_t)(kb + 48 + nh * 64) * 96 + np * 32 + c4];
            }
            if (hh == 0) {
                const float4 bb = *(const float4*)&inb[p * 128 + c0];
                A0 = bb.x; A1 = bb.y; A2 = bb.z; A3 = bb.w;
            }
            const float* __restrict__ W = wsh[hh];
            #pragma unroll 8
            for (int k2 = 0; k2 < 64; ++k2) {
                const float xv = xn[r][hh * 64 + k2];
                const float4 wk = *(const float4*)&W[k2 * 128 + c0];
                A0 = fmaf(xv, wk.x, A0); A1 = fmaf(xv, wk.y, A1);
                A2 = fmaf(xv, wk.z, A2); A3 = fmaf(xv, wk.w, A3);
            }
            if (!last) {
                float4* dst = (float4*)wsh[hh ^ 1];
                dst[t] = pf0; dst[t + 512] = pf1; dst[t + 1024] = pf2; dst[t + 1536] = pf3;
            }
            if (hh == 1) {
                if (p == 0) {          // Q: f32
                    *(float4*)&qkv[(size_t)row * 384 + c0] = make_float4(A0, A1, A2, A3);
                } else if (p == 1) {   // K: bf16 hi/lo, [h][key][d]
                    const int h = c0 >> 5, d = c0 & 31;
                    float A[4] = {A0, A1, A2, A3};
                    unsigned short h4[4], l4v[4];
                    #pragma unroll
                    for (int i = 0; i < 4; ++i) { h4[i] = f2bf(A[i]); l4v[i] = f2bf(A[i] - bf2f(h4[i])); }
                    *(uint2*)&Khi_g[((size_t)h * 4096 + row) * 32 + d] = *(uint2*)h4;
                    *(uint2*)&Klo_g[((size_t)h * 4096 + row) * 32 + d] = *(uint2*)l4v;
                } else {               // V: bf16, row-major [key][d] in LDS
                    unsigned short v4[4];
                    float A[4] = {A0, A1, A2, A3};
                    #pragma unroll
                    for (int i = 0; i < 4; ++i) v4[i] = f2bf(A[i]);
                    *(uint2*)&vsh[r][c0] = *(uint2*)v4;
                }
            }
        }
    }
    __syncthreads();
    if (t < 128) {   // V transpose flush: column d = t across 16 keys
        __align__(16) unsigned short tmp[16];
        #pragma unroll
        for (int k2 = 0; k2 < 16; ++k2) tmp[k2] = vsh[k2][t];
        *(uint4*)&Vt_g[(size_t)t * 4096 + r0]     = *(uint4*)&tmp[0];
        *(uint4*)&Vt_g[(size_t)t * 4096 + r0 + 8] = *(uint4*)&tmp[8];
    }
}

// ---------------- K3: MFMA flash attention — 2-phase double-buffered K/V staging ----------------
// Round-4 structure (1024 blocks, 4/CU): LDS-staged K/V, one barrier per chunk,
// chunk-uniform mask branch, lane-major conflict-free K staging writes.
#define KSTR 40
#define VSTR 72
#define PSTR 72

#define QK_TILES(MASKED)                                                        \
    _Pragma("unroll")                                                           \
    for (int tile = 0; tile < 4; ++tile) {                                      \
        const int kl = tile * 16 + l;                                           \
        const short8 kh = *(const short8*)&KhiC[kl * KSTR + quad * 8];          \
        const short8 kw = *(const short8*)&KloC[kl * KSTR + quad * 8];          \
        f32x4 S = {0.f, 0.f, 0.f, 0.f};                                         \
        __builtin_amdgcn_s_setprio(1);                                          \
        S = __builtin_amdgcn_mfma_f32_16x16x32_bf16(kh, qhi, S, 0, 0, 0);       \
        S = __builtin_amdgcn_mfma_f32_16x16x32_bf16(kw, qhi, S, 0, 0, 0);       \
        S = __builtin_amdgcn_mfma_f32_16x16x32_bf16(kh, qlo, S, 0, 0, 0);       \
        __builtin_amdgcn_s_setprio(0);                                          \
        const int kg0 = keybase + tile * 16 + quad * 4;                         \
        const float p0 = (!(MASKED) || (kg0 + 0 < nk)) ? __expf(S[0]) : 0.f;    \
        const float p1 = (!(MASKED) || (kg0 + 1 < nk)) ? __expf(S[1]) : 0.f;    \
        const float p2 = (!(MASKED) || (kg0 + 2 < nk)) ? __expf(S[2]) : 0.f;    \
        const float p3 = (!(MASKED) || (kg0 + 3 < nk)) ? __expf(S[3]) : 0.f;    \
        elane += (p0 + p1) + (p2 + p3);                                         \
        *(uint2*)&Pw[l * PSTR + tile * 16 + quad * 4] =                         \
            make_uint2(pk_bf16(p0, p1), pk_bf16(p2, p3));                       \
    }

__global__ __launch_bounds__(256) void k_attn(const float* __restrict__ qkv,
    const unsigned short* __restrict__ Khi_g, const unsigned short* __restrict__ Klo_g,
    const unsigned short* __restrict__ Vt_g,
    const int* __restrict__ sele, float* __restrict__ Oe, float* __restrict__ E)
{
    __shared__ __align__(16) unsigned short Khi[2][64 * KSTR];
    __shared__ __align__(16) unsigned short Klo[2][64 * KSTR];
    __shared__ __align__(16) unsigned short Vt[2][32 * VSTR];
    __shared__ __align__(16) unsigned short Pb[4][16 * PSTR];

    const int t = threadIdx.x;
    const int lane = t & 63;
    const int l = lane & 15;
    const int quad = lane >> 4;
    const int wv = __builtin_amdgcn_readfirstlane(t >> 6);
    const int qb = blockIdx.x;
    const int h  = blockIdx.y;
    const int ks = blockIdx.z;
    const int nk = sele[0];

    short8 qhi, qlo;
    {
        const float* __restrict__ qr = qkv + (size_t)(qb * 64 + wv * 16 + l) * 384 + h * 32 + quad * 8;
        const float4 a = *(const float4*)qr;
        const float4 b = *(const float4*)(qr + 4);
        const float sc = 0.17677669529663687f;   // 1/sqrt(32)
        float v[8] = {a.x * sc, a.y * sc, a.z * sc, a.w * sc, b.x * sc, b.y * sc, b.z * sc, b.w * sc};
        #pragma unroll
        for (int j = 0; j < 8; ++j) {
            const unsigned short hb = f2bf(v[j]);
            qhi[j] = (short)hb;
            qlo[j] = (short)f2bf(v[j] - bf2f(hb));
        }
    }
    f32x4 accO0 = {0.f, 0.f, 0.f, 0.f};
    f32x4 accO1 = {0.f, 0.f, 0.f, 0.f};
    float elane = 0.f;

    // K staging: lane-major keys, one d-quarter per wave (conflict-free LDS batches)
    const int kk = t & 63;           // key within chunk
    const int d0 = (t >> 6) * 8;     // 0,8,16,24
    const int vd = t >> 3;           // 0..31 d
    const int ko = (t & 7) * 8;      // 0..56 key offset

    const unsigned short* __restrict__ pKhi = Khi_g + ((size_t)h * 4096 + ks * 1024 + kk) * 32 + d0;
    const unsigned short* __restrict__ pKlo = Klo_g + ((size_t)h * 4096 + ks * 1024 + kk) * 32 + d0;
    const unsigned short* __restrict__ pVt  = Vt_g  + ((size_t)h * 32 + vd) * 4096 + ks * 1024 + ko;

    // prologue: chunk 0 -> buf0
    uint4 kh_n = *(const uint4*)pKhi;
    uint4 kl_n = *(const uint4*)pKlo;
    uint4 vv_n = *(const uint4*)pVt;
    *(uint4*)&Khi[0][kk * KSTR + d0] = kh_n;
    *(uint4*)&Klo[0][kk * KSTR + d0] = kl_n;
    *(uint4*)&Vt[0][vd * VSTR + ko]  = vv_n;

    for (int ch = 0; ch < 16; ++ch) {
        __syncthreads();                          // buf[ch&1] ready; prev reads of buf[ch^1] done
        const int cur = ch & 1;
        if (ch < 15) {                            // issue next chunk's loads (latency hides under MFMA)
            kh_n = *(const uint4*)(pKhi + (size_t)(ch + 1) * 2048);
            kl_n = *(const uint4*)(pKlo + (size_t)(ch + 1) * 2048);
            vv_n = *(const uint4*)(pVt  + (ch + 1) * 64);
        }
        const int keybase = ks * 1024 + ch * 64;
        const unsigned short* __restrict__ KhiC = Khi[cur];
        const unsigned short* __restrict__ KloC = Klo[cur];
        const unsigned short* __restrict__ VtC  = Vt[cur];
        unsigned short* __restrict__ Pw = Pb[wv];
        if (keybase + 64 <= nk) {                 // wave-uniform: no per-key masking
            QK_TILES(0)
        } else {
            QK_TILES(1)
        }
        #pragma unroll
        for (int step = 0; step < 2; ++step) {
            const short8 pa  = *(const short8*)&Pw[l * PSTR + step * 32 + quad * 8];
            const short8 vb0 = *(const short8*)&VtC[l * VSTR + step * 32 + quad * 8];
            const short8 vb1 = *(const short8*)&VtC[(16 + l) * VSTR + step * 32 + quad * 8];
            __builtin_amdgcn_s_setprio(1);
            accO0 = __builtin_amdgcn_mfma_f32_16x16x32_bf16(pa, vb0, accO0, 0, 0, 0);
            accO1 = __builtin_amdgcn_mfma_f32_16x16x32_bf16(pa, vb1, accO1, 0, 0, 0);
            __builtin_amdgcn_s_setprio(0);
        }
        if (ch < 15) {                            // write next chunk -> other buffer
            *(uint4*)&Khi[cur ^ 1][kk * KSTR + d0] = kh_n;
            *(uint4*)&Klo[cur ^ 1][kk * KSTR + d0] = kl_n;
            *(uint4*)&Vt[cur ^ 1][vd * VSTR + ko]  = vv_n;
        }
    }
    elane += __shfl_xor(elane, 16, 64);
    elane += __shfl_xor(elane, 32, 64);
    const int qrow0 = qb * 64 + wv * 16;
    if (lane < 16)
        E[((size_t)ks * 4 + h) * 4096 + qrow0 + l] = elane;
    #pragma unroll
    for (int r = 0; r < 4; ++r) {
        const size_t row = qrow0 + quad * 4 + r;
        Oe[((size_t)ks * 4096 + row) * 128 + h * 32 + l]      = accO0[r];
        Oe[((size_t)ks * 4096 + row) * 128 + h * 32 + 16 + l] = accO1[r];
    }
}

// ---------------- K4: fold + out-proj + residual + LN2 + FFN + column-sum ----------------
// 16 rows/block, 256 blocks, 512 threads. Half-panel double-buffered weight staging;
// 6 GEMM half-phases (outW, W1, W2 x 2 halves), one barrier each.
__global__ __launch_bounds__(512) void k_ffn(const float* __restrict__ eig,
    const float* __restrict__ Oe, const float* __restrict__ E,
    const float* __restrict__ outW, const float* __restrict__ outb,
    const float* __restrict__ lg, const float* __restrict__ lb,
    const float* __restrict__ W1, const float* __restrict__ b1,
    const float* __restrict__ W2, const float* __restrict__ b2,
    const int* __restrict__ sele, float* __restrict__ xsum)
{
    __shared__ __align__(16) float wsh[2][64 * 128];  // 2 x 32 KB half-panels
    __shared__ __align__(16) float sA[16][132];       // O rows, later gelu(h)
    __shared__ __align__(16) float xn[16][132];       // LN2 output
    __shared__ __align__(16) float cs[16][132];       // per-row masked contributions
    const int t = threadIdx.x;                        // 0..511
    const int r0 = blockIdx.x * 16;
    const int r  = t >> 5;
    const int c0 = (t & 31) * 4;

    const float4* __restrict__ Wp0 = (const float4*)outW;
    const float4* __restrict__ Wp1 = (const float4*)W1;
    const float4* __restrict__ Wp2 = (const float4*)W2;

    // prefetch outW h0 before fold
    float4 pf0 = Wp0[t], pf1 = Wp0[t + 512], pf2 = Wp0[t + 1024], pf3 = Wp0[t + 1536];

    {   // fold 4 key-slots + divide by E
        const int h = c0 >> 5;
        float es = 0.f;
        float v[4] = {0.f, 0.f, 0.f, 0.f};
        #pragma unroll
        for (int ks = 0; ks < KSPLIT; ++ks) {
            es += E[((size_t)ks * 4 + h) * 4096 + r0 + r];
            const float4 o1 = *(const float4*)&Oe[((size_t)ks * 4096 + r0 + r) * 128 + c0];
            v[0] += o1.x; v[1] += o1.y; v[2] += o1.z; v[3] += o1.w;
        }
        const float rcp = 1.f / es;
        *(float4*)&sA[r][c0] = make_float4(v[0] * rcp, v[1] * rcp, v[2] * rcp, v[3] * rcp);
    }
    {   float4* dst = (float4*)wsh[0];
        dst[t] = pf0; dst[t + 512] = pf1; dst[t + 1024] = pf2; dst[t + 1536] = pf3;
    }

    float x2[4];
    float A0, A1, A2, A3;
    #pragma unroll
    for (int gphase = 0; gphase < 6; ++gphase) {
        const int gg = gphase >> 1, hh = gphase & 1;
        __syncthreads();
        if (gphase < 5) {
            const int nid = gphase + 1;
            const int ng = nid >> 1, nh = nid & 1;
            const float4* __restrict__ src = (ng == 0) ? Wp0 : (ng == 1 ? Wp1 : Wp2);
            pf0 = src[nh * 2048 + t];        pf1 = src[nh * 2048 + t + 512];
            pf2 = src[nh * 2048 + t + 1024]; pf3 = src[nh * 2048 + t + 1536];
        }
        if (hh == 0) {
            const float* bias = (gg == 0) ? outb : (gg == 1 ? b1 : b2);
            const float4 bb = *(const float4*)&bias[c0];
            A0 = bb.x; A1 = bb.y; A2 = bb.z; A3 = bb.w;
        }
        const float* __restrict__ W = wsh[hh];
        const float* __restrict__ act = (gg == 1) ? &xn[r][0] : &sA[r][0];
        #pragma unroll 8
        for (int k2 = 0; k2 < 64; ++k2) {
            const float xv = act[hh * 64 + k2];
            const float4 wk = *(const float4*)&W[k2 * 128 + c0];
            A0 = fmaf(xv, wk.x, A0); A1 = fmaf(xv, wk.y, A1);
            A2 = fmaf(xv, wk.z, A2); A3 = fmaf(xv, wk.w, A3);
        }
        if (gphase < 5) {
            float4* dst = (float4*)wsh[hh ^ 1];
            dst[t] = pf0; dst[t + 512] = pf1; dst[t + 1024] = pf2; dst[t + 1536] = pf3;
        }
        if (hh == 1) {
            if (gg == 0) {      // residual + LN2 -> xn (half-wave local)
                const float4 ea = *(const float4*)&eig[(size_t)(r0 + r) * 128 + c0];
                x2[0] = ea.x + A0; x2[1] = ea.y + A1; x2[2] = ea.z + A2; x2[3] = ea.w + A3;
                float sa = (x2[0] + x2[1]) + (x2[2] + x2[3]);
                float qa = (x2[0] * x2[0] + x2[1] * x2[1]) + (x2[2] * x2[2] + x2[3] * x2[3]);
                #pragma unroll
                for (int m = 1; m < 32; m <<= 1) {
                    sa += __shfl_xor(sa, m, 32); qa += __shfl_xor(qa, m, 32);
                }
                const float ma = sa * (1.f / 128.f);
                const float ia = 1.f / sqrtf(qa * (1.f / 128.f) - ma * ma + 1e-5f);
                const float4 gg4 = *(const float4*)&lg[c0];
                const float4 bb4 = *(const float4*)&lb[c0];
                *(float4*)&xn[r][c0] = make_float4((x2[0] - ma) * ia * gg4.x + bb4.x,
                                                   (x2[1] - ma) * ia * gg4.y + bb4.y,
                                                   (x2[2] - ma) * ia * gg4.z + bb4.z,
                                                   (x2[3] - ma) * ia * gg4.w + bb4.w);
            } else if (gg == 1) {   // exact gelu -> sA (half-wave local)
                *(float4*)&sA[r][c0] = make_float4(
                    0.5f * A0 * (1.f + erff(A0 * 0.70710678118654752f)),
                    0.5f * A1 * (1.f + erff(A1 * 0.70710678118654752f)),
                    0.5f * A2 * (1.f + erff(A2 * 0.70710678118654752f)),
                    0.5f * A3 * (1.f + erff(A3 * 0.70710678118654752f)));
            } else {                // FFN2 + residual + masked contributions
                const int nsel = sele[0];
                const bool ina = (r0 + r) < nsel;
                *(float4*)&cs[r][c0] = ina ? make_float4(x2[0] + A0, x2[1] + A1, x2[2] + A2, x2[3] + A3)
                                           : make_float4(0.f, 0.f, 0.f, 0.f);
            }
        }
    }
    __syncthreads();
    if (t < 128) {
        float s = 0.f;
        #pragma unroll
        for (int rr = 0; rr < 16; ++rr) s += cs[rr][t];
        atomicAdd(&xsum[t], s);
    }
}

// ---------------- K5+K6 merged: coefficients (redundant per block) + Chebyshev ----------------
// 256 blocks x 128 threads, 16 eigenvalues/block; thread = one (elem, chain) pair.
__global__ __launch_bounds__(128) void k_tail(const float* __restrict__ eve,
    const float* __restrict__ xsum,
    const float* __restrict__ dscW, const float* __restrict__ dscb,
    const float* __restrict__ dwvW, const float* __restrict__ dwvb,
    const float* __restrict__ dssW, const float* __restrict__ dssb,
    const int* __restrict__ len, const int* __restrict__ sele,
    float* __restrict__ out)
{
    __shared__ float xs[128];
    __shared__ float val[104];
    __shared__ float s2[2];
    __shared__ float csc[50], cwv[50], cssh[4];
    __shared__ float sv[16][6];
    const int t = threadIdx.x;
    xs[t] = xsum[t];
    __syncthreads();
    if (t < 104) {
        const float invl = 1.f / ((float)len[0] + 1e-8f);
        const float ns = (float)sele[0];
        const float* Wp; int stride, col; float bias;
        if (t < 50)       { Wp = dscW; stride = 50; col = t;       bias = dscb[t]; }
        else if (t < 100) { Wp = dwvW; stride = 50; col = t - 50;  bias = dwvb[t - 50]; }
        else              { Wp = dssW; stride = 4;  col = t - 100; bias = dssb[t - 100]; }
        float a = 0.f;
        #pragma unroll 4
        for (int k = 0; k < 128; ++k) a = fmaf(xs[k], Wp[k * stride + col], a);
        a = (a + ns * bias) * invl;
        val[t] = 1.f / (1.f + __expf(-a));
    }
    __syncthreads();
    if (t == 0) { float s = 0.f; for (int i = 0; i < 50; ++i) s += val[i]; s2[0] = s; }
    if (t == 1) { float s = 0.f; for (int i = 0; i < 50; ++i) s += val[50 + i]; s2[1] = s; }
    __syncthreads();
    if (t < 50) {
        csc[t] = val[t] / (s2[0] + 1e-8f);
        cwv[t] = val[50 + t] / (s2[1] + 1e-8f);
    } else if (t >= 100 && t < 104) {
        cssh[t - 100] = val[t] * 5.0f;   // THRE
    }
    __syncthreads();
    const int e_i = t / 5, c = t - e_i * 5;       // elem 0..15, chain 0..4
    if (t < 80) {
        const float e = eve[blockIdx.x * 16 + e_i];
        float y;
        if (c == 0) y = e - 1.f;
        else { float f = e * cssh[c - 1]; if (f > 2.f) f = 0.f; y = f - 1.f; }
        const float* __restrict__ cf = (c == 0) ? csc : cwv;
        float te = 1.f, to = y;
        float u = (c == 0) ? to : te;
        float a = cf[0] * (0.5f * (1.f - u));
        const float y2 = 2.f * y;
        for (int i = 1; i < 50; ++i) {
            te = fmaf(y2, to, -te);
            to = fmaf(y2, te, -to);
            u = (c == 0) ? to : te;
            a = fmaf(cf[i], 0.5f * (1.f - u), a);
        }
        sv[e_i][c] = a;
    }
    __syncthreads();
    if (t < 80) {
        float n2 = 0.f;
        #pragma unroll
        for (int k = 0; k < 5; ++k) n2 += sv[e_i][k] * sv[e_i][k];
        const float invn = 1.f / (sqrtf(n2) + 1e-8f);
        out[(size_t)(blockIdx.x * 16 + e_i) * 5 + c] = sv[e_i][c] * invn;
    }
}

extern "C" void kernel_launch(void* const* d_in, const int* in_sizes, int n_in,
                              void* d_out, int out_size, void* d_ws, size_t ws_size,
                              hipStream_t stream) {
    const float* eve  = (const float*)d_in[0];
    const int*   len  = (const int*)d_in[1];
    const int*   sele = (const int*)d_in[2];
    const float* eigW = (const float*)d_in[3];
    const float* eigB = (const float*)d_in[4];
    const float* mlg  = (const float*)d_in[5];
    const float* mlb  = (const float*)d_in[6];
    const float* inW  = (const float*)d_in[7];
    const float* inb  = (const float*)d_in[8];
    const float* outW = (const float*)d_in[9];
    const float* outb = (const float*)d_in[10];
    const float* flg  = (const float*)d_in[11];
    const float* flb  = (const float*)d_in[12];
    const float* W1   = (const float*)d_in[13];
    const float* b1   = (const float*)d_in[14];
    const float* W2   = (const float*)d_in[15];
    const float* b2   = (const float*)d_in[16];
    const float* dscW = (const float*)d_in[17];
    const float* dscb = (const float*)d_in[18];
    const float* dwvW = (const float*)d_in[19];
    const float* dwvb = (const float*)d_in[20];
    const float* dssW = (const float*)d_in[21];
    const float* dssb = (const float*)d_in[22];

    float* ws   = (float*)d_ws;
    float* eig  = ws;
    float* qkv  = ws + 524288;
    float* Oe   = ws + 2097152;
    float* E    = ws + 4194304;
    float* xsum = ws + 4259840;
    unsigned short* Khi_g = (unsigned short*)(ws + 4260352);
    unsigned short* Klo_g = (unsigned short*)(ws + 4522496);
    unsigned short* Vt_g  = (unsigned short*)(ws + 4784640);
    float* out  = (float*)d_out;

    k_embed<<<256, 512, 0, stream>>>(eve, eigW, eigB, mlg, mlb, inW, inb,
                                     eig, qkv, Khi_g, Klo_g, Vt_g, xsum);
    k_attn <<<dim3(64, 4, KSPLIT), 256, 0, stream>>>(qkv, Khi_g, Klo_g, Vt_g, sele, Oe, E);
    k_ffn  <<<256, 512, 0, stream>>>(eig, Oe, E, outW, outb, flg, flb, W1, b1, W2, b2, sele, xsum);
    k_tail <<<256, 128, 0, stream>>>(eve, xsum, dscW, dscb, dwvW, dwvb, dssW, dssb, len, sele, out);
}